// Round 10
// baseline (61.424 us; speedup 1.0000x reference)
//
#include <hip/hip_runtime.h>

namespace {

constexpr int B = 8, C = 4, K = 5;
constexpr int HW = 512 * 1024;  // pixels per (b,c) plane
constexpr int NG = HW / 4;      // float4 groups per plane (131072)
constexpr int NT = 256;         // threads per block
constexpr int GPB = 64;         // blocks per batch
constexpr int NBLK = GPB * B;   // 512 blocks total = 2/CU -> co-resident
constexpr int SST = GPB * NT;   // 16384 group stride; 8 groups per thread
constexpr float DV = 0.5f;      // DELTA_V
constexpr float DD = 3.0f;      // DELTA_D
constexpr double FXST = 16777216.0;       // 2^24 stats fixed-point scale
constexpr double FXSV = 1099511627776.0;  // 2^40 var fixed-point scale

// ws float layout. Every RMW'd u64/u32 slot owns a 128B line (32 floats):
//   st   [B*25] u64 : fixed-point per-(b,slot) sums {4 ch sums, count}x5,
//                     64 integer atomicAdds each (associative=deterministic)
//   bc1  [B] u32    : phase-1 arrival counters (spin target)
//   iacc [B] u64    : fixed-point var accumulators
//   bc2  [B] u32    : phase-3 arrival counters
//   gc   u32        : global arrival counter
// ALL zeroed by zero_kernel (node 0) every call -> init-independent.
constexpr int ST_OFF = 0;
constexpr int BC1_OFF = ST_OFF + B * 25 * 32;  // 6400
constexpr int IACC_OFF = BC1_OFF + B * 32;     // 6656
constexpr int BC2_OFF = IACC_OFF + B * 32;     // 6912
constexpr int GC_OFF = BC2_OFF + B * 32;       // 7168
constexpr int WS_FLOATS = GC_OFF + 32;         // 7200 (28.8 KB)

__device__ __forceinline__ float wave_reduce(float v) {
#pragma unroll
  for (int m = 32; m; m >>= 1) v += __shfl_xor(v, m, 64);
  return v;
}

__global__ __launch_bounds__(NT) void zero_kernel(float* __restrict__ ws) {
  for (int i = threadIdx.x; i < WS_FLOATS; i += NT) ws[i] = 0.f;
}

__global__ __launch_bounds__(NT, 2) void fused_kernel(
    const float* __restrict__ emb, const int* __restrict__ lab,
    float* __restrict__ ws, float* __restrict__ out) {
  const int b = blockIdx.x >> 6, bxl = blockIdx.x & (GPB - 1);
  const int tid = threadIdx.x, wv = tid >> 6, ln = tid & 63;

  const float4* __restrict__ ep =
      reinterpret_cast<const float4*>(emb + (size_t)b * C * HW);
  const int4* __restrict__ lp =
      reinterpret_cast<const int4*>(lab + (size_t)b * HW);
  const int gbase = bxl * NT + tid;

  // ---------------- Phase 1: label counts + channel sums ------------------
  float acc[25];  // [k][{c0..c3,cnt}] flat, compile-time indexed only
#pragma unroll
  for (int i = 0; i < 25; i++) acc[i] = 0.f;

  auto accum1 = [&](int l, float v0, float v1, float v2, float v3) {
#pragma unroll
    for (int k = 0; k < K; k++) {  // branchless predicated accumulate
      const float m = (l == k + 1) ? 1.f : 0.f;
      acc[k * 5 + 0] = fmaf(m, v0, acc[k * 5 + 0]);
      acc[k * 5 + 1] = fmaf(m, v1, acc[k * 5 + 1]);
      acc[k * 5 + 2] = fmaf(m, v2, acc[k * 5 + 2]);
      acc[k * 5 + 3] = fmaf(m, v3, acc[k * 5 + 3]);
      acc[k * 5 + 4] += m;
    }
  };
#pragma unroll 1
  for (int seg = 0; seg < 4; seg++) {  // 8 groups = 4 x straight-line pairs
    const int g0 = gbase + (2 * seg) * SST, g1 = g0 + SST;
    const int4 la = lp[g0], lb2 = lp[g1];
    const float4 a0 = ep[g0], a1 = ep[NG + g0], a2 = ep[2 * NG + g0],
                 a3 = ep[3 * NG + g0];
    const float4 b0 = ep[g1], b1 = ep[NG + g1], b2 = ep[2 * NG + g1],
                 b3 = ep[3 * NG + g1];
    accum1(la.x, a0.x, a1.x, a2.x, a3.x);
    accum1(la.y, a0.y, a1.y, a2.y, a3.y);
    accum1(la.z, a0.z, a1.z, a2.z, a3.z);
    accum1(la.w, a0.w, a1.w, a2.w, a3.w);
    accum1(lb2.x, b0.x, b1.x, b2.x, b3.x);
    accum1(lb2.y, b0.y, b1.y, b2.y, b3.y);
    accum1(lb2.z, b0.z, b1.z, b2.z, b3.z);
    accum1(lb2.w, b0.w, b1.w, b2.w, b3.w);
  }

  __shared__ float red[4][25];
#pragma unroll
  for (int i = 0; i < 25; i++) {
    const float v = wave_reduce(acc[i]);
    if (ln == 0) red[wv][i] = v;
  }
  __syncthreads();
  // publish partials: 64 integer atomicAdds per slot, order-independent
  if (tid < 25) {
    const float t =
        (red[0][tid] + red[1][tid]) + (red[2][tid] + red[3][tid]);
    const long long q = (long long)((double)t * FXST);
    atomicAdd(reinterpret_cast<unsigned long long*>(ws + ST_OFF +
                                                    (b * 25 + tid) * 32),
              (unsigned long long)q);
  }
  // arrive (wave-0 vmcnt drains the 25 publishes first), then spin
  if (tid == 0) {
    asm volatile("s_waitcnt vmcnt(0)" ::: "memory");
    unsigned* c1 = reinterpret_cast<unsigned*>(ws + BC1_OFF + b * 32);
    atomicAdd(c1, 1u);
    while (__hip_atomic_load(c1, __ATOMIC_RELAXED,
                             __HIP_MEMORY_SCOPE_AGENT) < (unsigned)GPB) {
      __builtin_amdgcn_s_sleep(2);
    }
  }
  __syncthreads();
  asm volatile("" ::: "memory");

  // ---------------- Phase 2: read batch stats -> means --------------------
  __shared__ float stot[25];
  if (tid < 25) {
    const unsigned long long raw = __hip_atomic_load(
        reinterpret_cast<const unsigned long long*>(ws + ST_OFF +
                                                    (b * 25 + tid) * 32),
        __ATOMIC_RELAXED, __HIP_MEMORY_SCOPE_AGENT);
    stot[tid] = (float)((double)(long long)raw / FXST);
  }
  __syncthreads();
  __shared__ float sm[K][C];
  __shared__ float scnt[K];
  if (tid < K * C) {
    const int k = tid / C, c = tid % C;
    sm[k][c] = stot[k * 5 + c] / stot[k * 5 + 4];
  }
  if (tid < K) scnt[tid] = stot[tid * 5 + 4];
  __syncthreads();

  // ------- Phase 3: masked relu(||e-mean||-DV)^2 (re-read: L2/L3-hot) -----
  float vacc[K] = {0.f, 0.f, 0.f, 0.f, 0.f};
  auto accum2 = [&](int l, float v0, float v1, float v2, float v3) {
    const int kk = (l > 0) ? (l - 1) : 0;  // safe index; l==0 masked below
    const float d0 = v0 - sm[kk][0];
    const float d1 = v1 - sm[kk][1];
    const float d2 = v2 - sm[kk][2];
    const float d3 = v3 - sm[kk][3];
    const float t =
        fmaxf(sqrtf(d0 * d0 + d1 * d1 + d2 * d2 + d3 * d3) - DV, 0.f);
    const float t2 = t * t;
#pragma unroll
    for (int k = 0; k < K; k++) vacc[k] += (l == k + 1) ? t2 : 0.f;
  };
#pragma unroll 1
  for (int seg = 0; seg < 4; seg++) {
    const int g0 = gbase + (2 * seg) * SST, g1 = g0 + SST;
    const int4 la = lp[g0], lb2 = lp[g1];
    const float4 a0 = ep[g0], a1 = ep[NG + g0], a2 = ep[2 * NG + g0],
                 a3 = ep[3 * NG + g0];
    const float4 b0 = ep[g1], b1 = ep[NG + g1], b2 = ep[2 * NG + g1],
                 b3 = ep[3 * NG + g1];
    accum2(la.x, a0.x, a1.x, a2.x, a3.x);
    accum2(la.y, a0.y, a1.y, a2.y, a3.y);
    accum2(la.z, a0.z, a1.z, a2.z, a3.z);
    accum2(la.w, a0.w, a1.w, a2.w, a3.w);
    accum2(lb2.x, b0.x, b1.x, b2.x, b3.x);
    accum2(lb2.y, b0.y, b1.y, b2.y, b3.y);
    accum2(lb2.z, b0.z, b1.z, b2.z, b3.z);
    accum2(lb2.w, b0.w, b1.w, b2.w, b3.w);
  }

  __shared__ float red2[4][K];
#pragma unroll
  for (int i = 0; i < K; i++) {
    const float v = wave_reduce(vacc[i]);
    if (ln == 0) red2[wv][i] = v;
  }
  __syncthreads();

  // fold s_b via per-batch fixed-point atomic, then arrival counters
  __shared__ unsigned lastFlag;
  if (tid == 0) {
    float sblk = 0.f;
#pragma unroll
    for (int k = 0; k < K; k++) {
      sblk += ((red2[0][k] + red2[1][k]) + (red2[2][k] + red2[3][k])) /
              scnt[k];
    }
    const unsigned long long fx =
        (unsigned long long)(long long)((double)sblk * FXSV);
    atomicAdd(
        reinterpret_cast<unsigned long long*>(ws + IACC_OFF + b * 32), fx);
    asm volatile("s_waitcnt vmcnt(0)" ::: "memory");
    unsigned* bc2 = reinterpret_cast<unsigned*>(ws + BC2_OFF + b * 32);
    const unsigned oldb = atomicAdd(bc2, 1u);
    unsigned lf = 0u;
    if (oldb == (unsigned)(GPB - 1)) {  // batch-last block
      asm volatile("s_waitcnt vmcnt(0)" ::: "memory");
      unsigned* gc = reinterpret_cast<unsigned*>(ws + GC_OFF);
      const unsigned oldg = atomicAdd(gc, 1u);
      lf = (oldg == (unsigned)(B - 1)) ? 1u : 0u;
    }
    lastFlag = lf;
  }
  __syncthreads();
  if (!lastFlag) return;

  // ---------------- Finalize (unique global-last block) -------------------
  __shared__ float stF[B * 25];
  if (tid < B * 25) {
    const unsigned long long raw = __hip_atomic_load(
        reinterpret_cast<const unsigned long long*>(ws + ST_OFF + tid * 32),
        __ATOMIC_RELAXED, __HIP_MEMORY_SCOPE_AGENT);
    stF[tid] = (float)((double)(long long)raw / FXST);
  }
  __shared__ float sb[B];
  if (tid < B) {
    const unsigned long long raw = __hip_atomic_load(
        reinterpret_cast<const unsigned long long*>(ws + IACC_OFF + tid * 32),
        __ATOMIC_RELAXED, __HIP_MEMORY_SCOPE_AGENT);
    sb[tid] = (float)((double)(long long)raw / FXSV);
  }
  __syncthreads();
  if (tid != 0) return;

  float v = 0.f, d = 0.f;
  for (int bb = 0; bb < B; bb++) {
    float m[K][C];
#pragma unroll
    for (int k = 0; k < K; k++) {
      const float cnt = stF[bb * 25 + k * 5 + 4];
#pragma unroll
      for (int c = 0; c < C; c++) m[k][c] = stF[bb * 25 + k * 5 + c] / cnt;
    }
    float p = 0.f;
#pragma unroll
    for (int i = 0; i < K; i++) {
#pragma unroll
      for (int j = 0; j < K; j++) {
        if (i == j) continue;  // diagonal term is exactly 0
        float dd = 0.f;
#pragma unroll
        for (int c = 0; c < C; c++) {
          const float t = m[i][c] - m[j][c];
          dd += t * t;
        }
        const float r = fmaxf(DD - sqrtf(dd), 0.f);
        p += r * r;
      }
    }
    v = (v + sb[bb]) / (float)K;
    d = (d + p) / (float)(2 * K * (K - 1));
  }
  out[0] = v / (float)B;
  out[1] = d / (float)B;
}

}  // namespace

extern "C" void kernel_launch(void* const* d_in, const int* in_sizes, int n_in,
                              void* d_out, int out_size, void* d_ws,
                              size_t ws_size, hipStream_t stream) {
  const float* emb = (const float*)d_in[0];
  const int* lab = (const int*)d_in[1];
  float* out = (float*)d_out;
  float* ws = (float*)d_ws;

  zero_kernel<<<1, NT, 0, stream>>>(ws);
  fused_kernel<<<NBLK, NT, 0, stream>>>(emb, lab, ws, out);
}